// Round 5
// baseline (2440.520 us; speedup 1.0000x reference)
//
#include <hip/hip_runtime.h>
#include <hip/hip_bf16.h>

// LSTM: S=512, B=128, I=256, H=512. Gates stacked (f,i,o,c) along dim0 of W/U.
// FP32 tensors; MFMA in bf16; epilogue/state fp32.
//
// Persistent cooperative kernel, 256 WGs x 256 thr (round-3 skeleton):
//   - 4 independent batch-groups x 32 rows; 64 WGs/group (8 H-cols each).
//   - Weight B-fragments in registers (ub[16]+wb[8]); h via IF$ (sc0 sc1).
//   - NEW vs round 3: per-WG epoch FLAGS (plain sc0sc1 store) instead of a
//     single contended atomic counter; 64-lane parallel poll; h_seq store
//     moved off the critical path; counted vmcnt(8) MFMA split.

#define S_LEN 512
#define BATCH 128
#define ISZ   256
#define HSZ   512

typedef __attribute__((ext_vector_type(8))) short  s16x8;
typedef __attribute__((ext_vector_type(4))) float  f32x4;
typedef __attribute__((ext_vector_type(2))) float  f32x2;

#define XOFF 4096                                   // bf16 x in ws (Tier A)
#define XBYTES ((size_t)S_LEN * BATCH * ISZ * 2)    // 32 MiB
#define HOFF (XOFF + XBYTES)
#define HBYTES ((size_t)2 * BATCH * HSZ * 2)        // 256 KiB
#define WS_NEED (HOFF + HBYTES)
#define HOFF_SMALL 4096                             // Tier B: h right after flags

__device__ __forceinline__ unsigned short f2bf(float f) {
    unsigned u = __float_as_uint(f);
    u += 0x7fffu + ((u >> 16) & 1u);                // RNE
    return (unsigned short)(u >> 16);
}

__device__ __forceinline__ s16x8 ld8f_bf(const float* p) {
    f32x4 a = *(const f32x4*)p;
    f32x4 b = *(const f32x4*)(p + 4);
    s16x8 r;
    r[0] = (short)f2bf(a[0]); r[1] = (short)f2bf(a[1]);
    r[2] = (short)f2bf(a[2]); r[3] = (short)f2bf(a[3]);
    r[4] = (short)f2bf(b[0]); r[5] = (short)f2bf(b[1]);
    r[6] = (short)f2bf(b[2]); r[7] = (short)f2bf(b[3]);
    return r;
}

__global__ void __launch_bounds__(256, 1)
cvt_x_kernel(const float* __restrict__ x, unsigned short* __restrict__ xbf, int n8) {
    int i = blockIdx.x * blockDim.x + threadIdx.x;
    const int stride = gridDim.x * blockDim.x;
    for (; i < n8; i += stride)
        *(s16x8*)(xbf + (size_t)i * 8) = ld8f_bf(x + (size_t)i * 8);
}

#define MFMA_BF16 __builtin_amdgcn_mfma_f32_16x16x32_bf16

template <bool BIGWS>
__global__ void __launch_bounds__(256, 1)
lstm_flag(const float* __restrict__ x,
          const float* __restrict__ W,
          const float* __restrict__ bW,
          const float* __restrict__ U,
          const float* __restrict__ bU,
          float* __restrict__ out,
          unsigned char* __restrict__ ws)
{
    __shared__ float g_lds[32][33];                 // gate-tile exchange (+1 pad)

    const int tid  = threadIdx.x;
    const int bid  = blockIdx.x;
    const int grp  = bid >> 6;                      // 4 groups of 32 batch rows
    const int wg   = bid & 63;
    const int jBase = wg * 8;                       // H-col base
    const int rBase = grp * 32;                     // batch-row base

    unsigned* flags = (unsigned*)ws;                // [grp*64 + wg], 1 KiB used
    unsigned* myflag = flags + (grp << 6) + wg;
    unsigned short* hb = (unsigned short*)(ws + (BIGWS ? HOFF : HOFF_SMALL));
    unsigned short* h0 = hb;
    unsigned short* h1 = hb + BATCH * HSZ;
    const unsigned short* xbf = (const unsigned short*)(ws + XOFF);

    // ---- wave geometry: 4 waves = 2x2 quadrants of the 32-row x 32-gate-col tile ----
    const int w    = tid >> 6;
    const int lane = tid & 63;
    const int l15  = lane & 15;
    const int lq   = lane >> 4;                     // k-group 0..3
    const int mq   = w >> 1, nq = w & 1;
    const int ncol = nq * 16 + l15;                 // WG-local gate-col 0..31
    const int gRow = (ncol >> 3) * HSZ + jBase + (ncol & 7);
    const float bias = bW[gRow] + bU[gRow];
    const int arow = rBase + mq * 16 + l15;         // batch row for A fragments

    // ---- step-invariant B fragments: straight from global fp32 -> bf16 regs ----
    s16x8 ub[16], wb[8];
    #pragma unroll
    for (int ki = 0; ki < 16; ++ki)
        ub[ki] = ld8f_bf(U + (size_t)gRow * HSZ + ki * 32 + lq * 8);
    #pragma unroll
    for (int ki = 0; ki < 8; ++ki)
        wb[ki] = ld8f_bf(W + (size_t)gRow * ISZ + ki * 32 + lq * 8);

    // ---- epilogue mapping: 128 threads x (1 row, 2 cols); c-state in regs ----
    const int er   = tid >> 2;                      // local row 0..31 (tid<128)
    const int ej0  = (tid & 3) * 2;                 // col pair 0,2,4,6
    const int orow = rBase + er;
    const int ocol = jBase + ej0;
    float c0 = 0.f, c1 = 0.f;

    for (int t = 0; t < S_LEN; ++t) {
        f32x4 acc  = { bias, bias, bias, bias };
        f32x4 acc2 = { 0.f, 0.f, 0.f, 0.f };

        // x @ W^T (K=256) -- no cross-WG dependency; overlaps producers' tail
        #pragma unroll
        for (int ki = 0; ki < 8; ++ki) {
            s16x8 a;
            if constexpr (BIGWS)
                a = *(const s16x8*)(xbf + ((size_t)t * BATCH + arow) * ISZ + lq * 8 + ki * 32);
            else
                a = ld8f_bf(x + ((size_t)t * BATCH + arow) * ISZ + lq * 8 + ki * 32);
            if (ki & 1) acc2 = MFMA_BF16(a, wb[ki], acc2, 0, 0, 0);
            else        acc  = MFMA_BF16(a, wb[ki], acc,  0, 0, 0);
        }

        if (t > 0) {
            // ---- wave-0 parallel poll: lane i watches WG i's flag ----
            if (tid < 64) {
                const unsigned* fp = flags + (grp << 6) + tid;
                const unsigned tgt = (unsigned)t;
                for (;;) {
                    unsigned v;
                    asm volatile("global_load_dword %0, %1, off sc0 sc1\n\t"
                                 "s_waitcnt vmcnt(0)"
                                 : "=v"(v) : "v"(fp) : "memory");
                    if (__all(v >= tgt)) break;
                    __builtin_amdgcn_s_sleep(1);
                }
            }
            __syncthreads();

            const unsigned short* hp = ((t & 1) ? h0 : h1) + (size_t)arow * HSZ + lq * 8;
            s16x8 f0,f1,f2,f3,f4,f5,f6,f7,f8,f9,f10,f11,f12,f13,f14,f15;
#define LDH(d, o) asm volatile("global_load_dwordx4 %0, %1, off offset:" o " sc0 sc1" \
                               : "=v"(d) : "v"(hp) : "memory")
            LDH(f0,"0");    LDH(f1,"64");   LDH(f2,"128");  LDH(f3,"192");
            LDH(f4,"256");  LDH(f5,"320");  LDH(f6,"384");  LDH(f7,"448");
            LDH(f8,"512");  LDH(f9,"576");  LDH(f10,"640"); LDH(f11,"704");
            LDH(f12,"768"); LDH(f13,"832"); LDH(f14,"896"); LDH(f15,"960");
#undef LDH
            asm volatile("s_waitcnt vmcnt(8)" ::: "memory");
            __builtin_amdgcn_sched_barrier(0);      // keep MFMAs below the wait
            acc  = MFMA_BF16(f0, ub[0], acc,  0, 0, 0);
            acc2 = MFMA_BF16(f1, ub[1], acc2, 0, 0, 0);
            acc  = MFMA_BF16(f2, ub[2], acc,  0, 0, 0);
            acc2 = MFMA_BF16(f3, ub[3], acc2, 0, 0, 0);
            acc  = MFMA_BF16(f4, ub[4], acc,  0, 0, 0);
            acc2 = MFMA_BF16(f5, ub[5], acc2, 0, 0, 0);
            acc  = MFMA_BF16(f6, ub[6], acc,  0, 0, 0);
            acc2 = MFMA_BF16(f7, ub[7], acc2, 0, 0, 0);
            asm volatile("s_waitcnt vmcnt(0)" ::: "memory");
            __builtin_amdgcn_sched_barrier(0);
            acc  = MFMA_BF16(f8,  ub[8],  acc,  0, 0, 0);
            acc2 = MFMA_BF16(f9,  ub[9],  acc2, 0, 0, 0);
            acc  = MFMA_BF16(f10, ub[10], acc,  0, 0, 0);
            acc2 = MFMA_BF16(f11, ub[11], acc2, 0, 0, 0);
            acc  = MFMA_BF16(f12, ub[12], acc,  0, 0, 0);
            acc2 = MFMA_BF16(f13, ub[13], acc2, 0, 0, 0);
            acc  = MFMA_BF16(f14, ub[14], acc,  0, 0, 0);
            acc2 = MFMA_BF16(f15, ub[15], acc2, 0, 0, 0);
        }

        #pragma unroll
        for (int r = 0; r < 4; ++r)
            g_lds[mq * 16 + lq * 4 + r][ncol] = acc[r] + acc2[r];
        __syncthreads();

        float hn0 = 0.f, hn1 = 0.f;
        if (tid < 128) {
            const float gf0 = g_lds[er][ej0],      gf1 = g_lds[er][ej0 + 1];
            const float gi0 = g_lds[er][ej0 + 8],  gi1 = g_lds[er][ej0 + 9];
            const float go0 = g_lds[er][ej0 + 16], go1 = g_lds[er][ej0 + 17];
            const float gc0 = g_lds[er][ej0 + 24], gc1 = g_lds[er][ej0 + 25];

            const float fg0 = 1.f / (1.f + __expf(-gf0));
            const float fg1 = 1.f / (1.f + __expf(-gf1));
            const float ig0 = 1.f / (1.f + __expf(-gi0));
            const float ig1 = 1.f / (1.f + __expf(-gi1));
            const float og0 = 1.f / (1.f + __expf(-go0));
            const float og1 = 1.f / (1.f + __expf(-go1));
            const float e0 = __expf(-2.f * fabsf(gc0));
            const float e1 = __expf(-2.f * fabsf(gc1));
            const float cd0 = copysignf((1.f - e0) / (1.f + e0), gc0);
            const float cd1 = copysignf((1.f - e1) / (1.f + e1), gc1);

            c0 = fg0 * c0 + ig0 * cd0;
            c1 = fg1 * c1 + ig1 * cd1;

            const float t0 = __expf(-2.f * fabsf(c0));
            const float t1 = __expf(-2.f * fabsf(c1));
            hn0 = og0 * copysignf((1.f - t0) / (1.f + t0), c0);
            hn1 = og1 * copysignf((1.f - t1) / (1.f + t1), c1);

            if (t < S_LEN - 1) {
                // publish h_t (bf16 pair) through the coherent point
                unsigned hwv = (unsigned)f2bf(hn0) | ((unsigned)f2bf(hn1) << 16);
                unsigned short* hd = ((t & 1) ? h1 : h0) + (size_t)orow * HSZ + ocol;
                asm volatile("global_store_dword %0, %1, off sc0 sc1"
                             :: "v"(hd), "v"(hwv) : "memory");
            }
        }

        if (t < S_LEN - 1) {
            asm volatile("s_waitcnt vmcnt(0)" ::: "memory");   // h stores acked at IF$
            __syncthreads();                                   // whole WG done
            if (tid == 0) {
                unsigned ep = (unsigned)(t + 1);
                asm volatile("global_store_dword %0, %1, off sc0 sc1"
                             :: "v"(myflag), "v"(ep) : "memory");
            }
            if (tid < 128) {                                   // h_seq off critical path
                f32x2 hv = { hn0, hn1 };
                *(f32x2*)(out + ((size_t)t * BATCH + orow) * HSZ + ocol) = hv;
            }
        } else if (tid < 128) {
            f32x2 hv = { hn0, hn1 };
            *(f32x2*)(out + ((size_t)t * BATCH + orow) * HSZ + ocol) = hv;
            const size_t HSEQ = (size_t)S_LEN * BATCH * HSZ;
            *(f32x2*)(out + HSEQ + (size_t)orow * HSZ + ocol) = hv;          // h_final
            f32x2 cv = { c0, c1 };
            *(f32x2*)(out + HSEQ + (size_t)BATCH * HSZ
                      + (size_t)orow * HSZ + ocol) = cv;                     // c_final
        }
    }
}

extern "C" void kernel_launch(void* const* d_in, const int* in_sizes, int n_in,
                              void* d_out, int out_size, void* d_ws, size_t ws_size,
                              hipStream_t stream) {
    const float* x  = (const float*)d_in[0];
    const float* W  = (const float*)d_in[1];
    const float* bW = (const float*)d_in[2];
    const float* U  = (const float*)d_in[3];
    const float* bU = (const float*)d_in[4];
    float* out = (float*)d_out;
    unsigned char* ws = (unsigned char*)d_ws;

    // epoch flags must be 0 at every launch (ws is not re-poisoned between replays)
    hipMemsetAsync(ws, 0, 4096, stream);

    void* args[] = { (void*)&x, (void*)&W, (void*)&bW, (void*)&U, (void*)&bU,
                     (void*)&out, (void*)&ws };

    if (ws_size >= WS_NEED) {
        const int n8 = S_LEN * BATCH * ISZ / 8;
        cvt_x_kernel<<<2048, 256, 0, stream>>>(x, (unsigned short*)(ws + XOFF), n8);
        hipError_t e = hipLaunchCooperativeKernel((void*)lstm_flag<true>, dim3(256),
                                                  dim3(256), args, 0, stream);
        if (e != hipSuccess)
            lstm_flag<true><<<dim3(256), dim3(256), 0, stream>>>(x, W, bW, U, bU, out, ws);
    } else {
        hipError_t e = hipLaunchCooperativeKernel((void*)lstm_flag<false>, dim3(256),
                                                  dim3(256), args, 0, stream);
        if (e != hipSuccess)
            lstm_flag<false><<<dim3(256), dim3(256), 0, stream>>>(x, W, bW, U, bU, out, ws);
    }
}

// Round 6
// 1698.628 us; speedup vs baseline: 1.4368x; 1.4368x over previous
//
#include <hip/hip_runtime.h>
#include <hip/hip_bf16.h>

// LSTM: S=512, B=128, I=256, H=512. Gates stacked (f,i,o,c) along dim0 of W/U.
// FP32 tensors; MFMA in bf16; epilogue/state fp32.
//
// Persistent cooperative kernel, 256 WGs x 256 thr:
//   - 4 independent batch-groups x 32 rows; 64 WGs/group (8 H-cols each).
//   - Wave split: (mq,nq) = (row-half, K-half). Each wave loads only its
//     K-half of h (8 frags) -> no duplicate IF$ traffic (8 MB/step total).
//   - Partial sums in two LDS planes g[2][32][33], summed in epilogue.
//   - Per-WAVE epoch flags (no pre-flag syncthreads, no tid0 bottleneck).
//   - Epilogue on all 256 threads (1 cell each), h published via store_short.

#define S_LEN 512
#define BATCH 128
#define ISZ   256
#define HSZ   512

typedef __attribute__((ext_vector_type(8))) short    s16x8;
typedef __attribute__((ext_vector_type(4))) float    f32x4;
typedef __attribute__((ext_vector_type(4))) unsigned u32x4;

#define HOFF   4096                                  // h ping-pong (bf16), fixed
#define HBYTES ((size_t)2 * BATCH * HSZ * 2)         // 262144
#define XOFF   (HOFF + HBYTES)                       // 266240, 4K-aligned
#define XBYTES ((size_t)S_LEN * BATCH * ISZ * 2)     // 32 MiB
#define WS_NEED (XOFF + XBYTES)

__device__ __forceinline__ unsigned short f2bf(float f) {
    unsigned u = __float_as_uint(f);
    u += 0x7fffu + ((u >> 16) & 1u);                 // RNE
    return (unsigned short)(u >> 16);
}

__device__ __forceinline__ s16x8 ld8f_bf(const float* p) {
    f32x4 a = *(const f32x4*)p;
    f32x4 b = *(const f32x4*)(p + 4);
    s16x8 r;
    r[0] = (short)f2bf(a[0]); r[1] = (short)f2bf(a[1]);
    r[2] = (short)f2bf(a[2]); r[3] = (short)f2bf(a[3]);
    r[4] = (short)f2bf(b[0]); r[5] = (short)f2bf(b[1]);
    r[6] = (short)f2bf(b[2]); r[7] = (short)f2bf(b[3]);
    return r;
}

__global__ void __launch_bounds__(256, 1)
cvt_x_kernel(const float* __restrict__ x, unsigned short* __restrict__ xbf, int n8) {
    int i = blockIdx.x * blockDim.x + threadIdx.x;
    const int stride = gridDim.x * blockDim.x;
    for (; i < n8; i += stride)
        *(s16x8*)(xbf + (size_t)i * 8) = ld8f_bf(x + (size_t)i * 8);
}

#define MFMA_BF16 __builtin_amdgcn_mfma_f32_16x16x32_bf16

template <bool BIGWS>
__global__ void __launch_bounds__(256, 1)
lstm_ks(const float* __restrict__ x,
        const float* __restrict__ W,
        const float* __restrict__ bW,
        const float* __restrict__ U,
        const float* __restrict__ bU,
        float* __restrict__ out,
        unsigned char* __restrict__ ws)
{
    __shared__ float g_lds[2][32][33];               // two K-half partial planes

    const int tid  = threadIdx.x;
    const int bid  = blockIdx.x;
    const int grp  = bid >> 6;                       // 4 groups of 32 batch rows
    const int wg   = bid & 63;
    const int jBase = wg * 8;                        // H-col base
    const int rBase = grp * 32;                      // batch-row base

    unsigned* flags = (unsigned*)ws;                 // [grp][wg][wave] dwords (4KiB)
    unsigned short* h0 = (unsigned short*)(ws + HOFF);
    unsigned short* h1 = h0 + BATCH * HSZ;
    const unsigned short* xbf = (const unsigned short*)(ws + XOFF);

    // ---- wave geometry: (mq,nq) = (row-half, K-half) ----
    const int wv   = tid >> 6;
    const int lane = tid & 63;
    const int l15  = lane & 15;
    const int lq   = lane >> 4;                      // k sub-group 0..3
    const int mq   = wv >> 1, nq = wv & 1;
    const int arow = rBase + mq * 16 + l15;          // batch row of A fragments

    // ---- step-invariant B fragments (both 16-col tiles, own K-half only) ----
    s16x8 ub[2][8], wb[2][4];
    float bias[2];
    #pragma unroll
    for (int n = 0; n < 2; ++n) {
        const int c = n * 16 + l15;                  // WG-local gate-col
        const int gRow = (c >> 3) * HSZ + jBase + (c & 7);
        bias[n] = (nq == 0) ? (bW[gRow] + bU[gRow]) : 0.f;
        #pragma unroll
        for (int ki = 0; ki < 8; ++ki)
            ub[n][ki] = ld8f_bf(U + (size_t)gRow * HSZ + nq * 256 + ki * 32 + lq * 8);
        #pragma unroll
        for (int ki = 0; ki < 4; ++ki)
            wb[n][ki] = ld8f_bf(W + (size_t)gRow * ISZ + nq * 128 + ki * 32 + lq * 8);
    }

    // ---- epilogue mapping: 256 threads x 1 cell ----
    const int er   = tid >> 3;                       // local row 0..31
    const int ej   = tid & 7;                        // local H-col 0..7
    const int orow = rBase + er;
    const int ocol = jBase + ej;
    float cst = 0.f;

    for (int t = 0; t < S_LEN; ++t) {
        f32x4 acc0 = { bias[0], bias[0], bias[0], bias[0] };
        f32x4 acc1 = { bias[1], bias[1], bias[1], bias[1] };

        // x @ W^T (own K-half) -- overlaps other WGs' release tails
        #pragma unroll
        for (int ki = 0; ki < 4; ++ki) {
            s16x8 a;
            if constexpr (BIGWS)
                a = *(const s16x8*)(xbf + ((size_t)t * BATCH + arow) * ISZ
                                    + nq * 128 + ki * 32 + lq * 8);
            else
                a = ld8f_bf(x + ((size_t)t * BATCH + arow) * ISZ
                            + nq * 128 + ki * 32 + lq * 8);
            acc0 = MFMA_BF16(a, wb[0][ki], acc0, 0, 0, 0);
            acc1 = MFMA_BF16(a, wb[1][ki], acc1, 0, 0, 0);
        }

        if (t > 0) {
            // ---- wave-0 poll: lane i checks WG i's 4 wave-flags (1 dwordx4) ----
            if (tid < 64) {
                const unsigned* fp = flags + (grp << 8) + (lane << 2);
                const unsigned tgt = (unsigned)t;
                for (;;) {
                    u32x4 fv;
                    asm volatile("global_load_dwordx4 %0, %1, off sc0 sc1\n\t"
                                 "s_waitcnt vmcnt(0)"
                                 : "=v"(fv) : "v"(fp) : "memory");
                    unsigned m0 = fv[0] < fv[1] ? fv[0] : fv[1];
                    unsigned m1 = fv[2] < fv[3] ? fv[2] : fv[3];
                    if (__all((m0 < m1 ? m0 : m1) >= tgt)) break;
                }
            }
            __syncthreads();

            // ---- h_{t-1} A-fragments: own K-half only (8 loads) ----
            const unsigned short* hp = ((t & 1) ? h0 : h1)
                                       + (size_t)arow * HSZ + nq * 256 + lq * 8;
            s16x8 f0,f1,f2,f3,f4,f5,f6,f7;
#define LDH(d, o) asm volatile("global_load_dwordx4 %0, %1, off offset:" o " sc0 sc1" \
                               : "=v"(d) : "v"(hp) : "memory")
            LDH(f0,"0");   LDH(f1,"64");  LDH(f2,"128"); LDH(f3,"192");
            LDH(f4,"256"); LDH(f5,"320"); LDH(f6,"384"); LDH(f7,"448");
#undef LDH
            asm volatile("s_waitcnt vmcnt(4)" ::: "memory");
            __builtin_amdgcn_sched_barrier(0);
            acc0 = MFMA_BF16(f0, ub[0][0], acc0, 0, 0, 0);
            acc1 = MFMA_BF16(f0, ub[1][0], acc1, 0, 0, 0);
            acc0 = MFMA_BF16(f1, ub[0][1], acc0, 0, 0, 0);
            acc1 = MFMA_BF16(f1, ub[1][1], acc1, 0, 0, 0);
            acc0 = MFMA_BF16(f2, ub[0][2], acc0, 0, 0, 0);
            acc1 = MFMA_BF16(f2, ub[1][2], acc1, 0, 0, 0);
            acc0 = MFMA_BF16(f3, ub[0][3], acc0, 0, 0, 0);
            acc1 = MFMA_BF16(f3, ub[1][3], acc1, 0, 0, 0);
            asm volatile("s_waitcnt vmcnt(0)" ::: "memory");
            __builtin_amdgcn_sched_barrier(0);
            acc0 = MFMA_BF16(f4, ub[0][4], acc0, 0, 0, 0);
            acc1 = MFMA_BF16(f4, ub[1][4], acc1, 0, 0, 0);
            acc0 = MFMA_BF16(f5, ub[0][5], acc0, 0, 0, 0);
            acc1 = MFMA_BF16(f5, ub[1][5], acc1, 0, 0, 0);
            acc0 = MFMA_BF16(f6, ub[0][6], acc0, 0, 0, 0);
            acc1 = MFMA_BF16(f6, ub[1][6], acc1, 0, 0, 0);
            acc0 = MFMA_BF16(f7, ub[0][7], acc0, 0, 0, 0);
            acc1 = MFMA_BF16(f7, ub[1][7], acc1, 0, 0, 0);
        }

        // ---- write K-half partials to own plane ----
        #pragma unroll
        for (int r = 0; r < 4; ++r) {
            g_lds[nq][mq * 16 + lq * 4 + r][l15]      = acc0[r];
            g_lds[nq][mq * 16 + lq * 4 + r][16 + l15] = acc1[r];
        }
        __syncthreads();

        // ---- epilogue: all 256 threads, one cell each ----
        const float gf = g_lds[0][er][ej]      + g_lds[1][er][ej];
        const float gi = g_lds[0][er][8 + ej]  + g_lds[1][er][8 + ej];
        const float go = g_lds[0][er][16 + ej] + g_lds[1][er][16 + ej];
        const float gc = g_lds[0][er][24 + ej] + g_lds[1][er][24 + ej];

        const float fg = 1.f / (1.f + __expf(-gf));
        const float ig = 1.f / (1.f + __expf(-gi));
        const float og = 1.f / (1.f + __expf(-go));
        const float ec = __expf(-2.f * fabsf(gc));
        const float cd = copysignf((1.f - ec) / (1.f + ec), gc);
        cst = fg * cst + ig * cd;
        const float eh = __expf(-2.f * fabsf(cst));
        const float hn = og * copysignf((1.f - eh) / (1.f + eh), cst);

        if (t < S_LEN - 1) {
            // publish h_t (bf16) -> IF$, ack, then per-wave flag
            unsigned hv = (unsigned)f2bf(hn);
            unsigned short* hd = ((t & 1) ? h1 : h0) + (size_t)orow * HSZ + ocol;
            asm volatile("global_store_short %0, %1, off sc0 sc1"
                         :: "v"(hd), "v"(hv) : "memory");
            asm volatile("s_waitcnt vmcnt(0)" ::: "memory");   // own wave's h acked
            if (lane == 0) {
                unsigned* fl = flags + (grp << 8) + (wg << 2) + wv;
                unsigned ep = (unsigned)(t + 1);
                asm volatile("global_store_dword %0, %1, off sc0 sc1"
                             :: "v"(fl), "v"(ep) : "memory");
            }
            out[((size_t)t * BATCH + orow) * HSZ + ocol] = hn;   // h_seq, off-path
        } else {
            out[((size_t)t * BATCH + orow) * HSZ + ocol] = hn;
            const size_t HSEQ = (size_t)S_LEN * BATCH * HSZ;
            out[HSEQ + (size_t)orow * HSZ + ocol] = hn;          // h_final
            out[HSEQ + (size_t)BATCH * HSZ + (size_t)orow * HSZ + ocol] = cst; // c_final
        }
    }
}

extern "C" void kernel_launch(void* const* d_in, const int* in_sizes, int n_in,
                              void* d_out, int out_size, void* d_ws, size_t ws_size,
                              hipStream_t stream) {
    const float* x  = (const float*)d_in[0];
    const float* W  = (const float*)d_in[1];
    const float* bW = (const float*)d_in[2];
    const float* U  = (const float*)d_in[3];
    const float* bU = (const float*)d_in[4];
    float* out = (float*)d_out;
    unsigned char* ws = (unsigned char*)d_ws;

    // per-wave epoch flags must be 0 at every launch
    hipMemsetAsync(ws, 0, 4096, stream);

    void* args[] = { (void*)&x, (void*)&W, (void*)&bW, (void*)&U, (void*)&bU,
                     (void*)&out, (void*)&ws };

    if (ws_size >= WS_NEED) {
        const int n8 = S_LEN * BATCH * ISZ / 8;
        cvt_x_kernel<<<2048, 256, 0, stream>>>(x, (unsigned short*)(ws + XOFF), n8);
        hipError_t e = hipLaunchCooperativeKernel((void*)lstm_ks<true>, dim3(256),
                                                  dim3(256), args, 0, stream);
        if (e != hipSuccess)
            lstm_ks<true><<<dim3(256), dim3(256), 0, stream>>>(x, W, bW, U, bU, out, ws);
    } else {
        hipError_t e = hipLaunchCooperativeKernel((void*)lstm_ks<false>, dim3(256),
                                                  dim3(256), args, 0, stream);
        if (e != hipSuccess)
            lstm_ks<false><<<dim3(256), dim3(256), 0, stream>>>(x, W, bW, U, bU, out, ws);
    }
}